// Round 4
// baseline (233.887 us; speedup 1.0000x reference)
//
#include <hip/hip_runtime.h>

// Depth-3 Haar wavelet packet transform along last dim (S=8192), rows = B*C = 4096.
// out[row, n*1024 + j] = c^3 * sum_t (-1)^(...) x[row, 8j+t], n = 4*b1+2*b2+b3.
//
// Persistent-wave streaming formulation (no __syncthreads anywhere):
//   - 8192 waves, each owns a half-row = 16 chunks of 256 floats (full unroll).
//   - per chunk: 1 coalesced 1KiB load -> levels 1-2 in-register -> level 3 via
//     shfl_xor(1) -> 4 scalar writes into the wave's PRIVATE 1KiB LDS region
//     (2-way bank aliasing = free) -> 1 ds_read_b128 (8-lane groups cover all
//     32 banks, conflict-free) -> 1 store instr = 8 dense 128B segments
//     (one per node). Same-wave DS ops complete in order -> no barrier needed.
//   - loads pipelined 2 chunks ahead: stores never gate loads, ~2KiB VMEM in
//     flight per wave, 32 waves/CU.

#define C3 0.35355339059327373f

__global__ __launch_bounds__(256) void swpt3_kernel(const float4* __restrict__ x,
                                                    float* __restrict__ out) {
    __shared__ float lds[1024];              // 4 waves x 256 floats (wave-private)
    const unsigned tid  = threadIdx.x;
    const unsigned lane = tid & 63u;
    const unsigned wid  = tid >> 6;

    float* W = lds + (wid << 8);             // this wave's 256-float region

    const unsigned gw   = blockIdx.x * 4u + wid;   // 0..8191
    const unsigned row  = gw >> 1;                 // 2 waves per row
    const unsigned half = gw & 1u;

    const float4* xh = x + (size_t)row * 2048u + (size_t)half * 1024u + lane;
    float* orow = out + (size_t)row * 8192u;

    const unsigned p  = lane & 1u;
    const unsigned jl = lane >> 1;           // j within chunk (0..31)

    float* w0 = W + p * 32u + jl;            // nb=0 slot; nb=2/4/6 at +64/+128/+192
    const float4* rd = (const float4*)W + lane;   // floats 4*lane .. 4*lane+3
    float* ob = orow + (lane >> 3) * 1024u + half * 512u + 4u * (lane & 7u);

    float4 v0 = xh[0];
    float4 v1 = xh[64];

    #pragma unroll
    for (unsigned i = 0; i < 16; ++i) {
        float4 vn = v1;                       // dummy for the last two iters
        if (i + 2u < 16u) vn = xh[(i + 2u) * 64u];

        // level 1 within the float4
        const float s0 = v0.x + v0.y, d0 = v0.x - v0.y;
        const float s1 = v0.z + v0.w, d1 = v0.z - v0.w;
        // level 2 (unscaled): node-base nb = 4*b1 + 2*b2
        const float e0 = s0 + s1;   // nb=0
        const float e2 = s0 - s1;   // nb=2
        const float e4 = d0 + d1;   // nb=4
        const float e6 = d0 - d1;   // nb=6

        // level 3: partner lane (xor 1) holds the other half-group
        const float f0 = __shfl_xor(e0, 1);
        const float f2 = __shfl_xor(e2, 1);
        const float f4 = __shfl_xor(e4, 1);
        const float f6 = __shfl_xor(e6, 1);

        const float r0 = (f0 + (p ? -e0 : e0)) * C3;   // node 0+p
        const float r2 = (f2 + (p ? -e2 : e2)) * C3;   // node 2+p
        const float r4 = (f4 + (p ? -e4 : e4)) * C3;   // node 4+p
        const float r6 = (f6 + (p ? -e6 : e6)) * C3;   // node 6+p

        // wave-private LDS transpose (no barrier: same-wave DS is in-order)
        w0[0]   = r0;
        w0[64]  = r2;
        w0[128] = r4;
        w0[192] = r6;

        __builtin_amdgcn_wave_barrier();      // pin write->read scheduling order

        const float4 r = *rd;                 // node lane>>3, j = 4*(lane&7)

        __builtin_amdgcn_wave_barrier();      // pin read before next iter's writes

        *(float4*)(ob + i * 32u) = r;         // 8 dense 128B segments per instr

        v0 = v1;
        v1 = vn;
    }
}

extern "C" void kernel_launch(void* const* d_in, const int* in_sizes, int n_in,
                              void* d_out, int out_size, void* d_ws, size_t ws_size,
                              hipStream_t stream) {
    const float4* x = (const float4*)d_in[0];
    float* out = (float*)d_out;
    // 8192 waves x 16 chunks x 256 floats = 33,554,432 floats = full tensor.
    swpt3_kernel<<<2048, 256, 0, stream>>>(x, out);
}

// Round 6
// 220.852 us; speedup vs baseline: 1.0590x; 1.0590x over previous
//
#include <hip/hip_runtime.h>

// Depth-3 Haar wavelet packet transform along last dim (S=8192), rows = B*C = 4096.
// out[row, n*1024 + j] = c^3 * sum_t (-1)^(b1*t0 + b2*t1 + b3*t2) x[row, 8j+t],
// n = 4*b1 + 2*b2 + b3, c^3 = 2^{-1.5}.
//
// Structure = R0 (best measured): block = 256 threads = one 1024-float chunk,
// float4 load -> 2-level in-register butterfly -> level-3 via shfl_xor(1) ->
// 4 scalar LDS writes (2-way aliasing, free) -> barrier -> ds_read_b128 ->
// one float4 store per thread.
//
// Round-6 change (single variable, fixed compile): NONTEMPORAL stores via a
// native ext_vector_type float4 (clang's builtin rejects HIP_vector_type).
// Output is write-once / never re-read; normal stores write-allocate in L2/L3
// and evict the (partially L3-resident) input mid-kernel — counters showed
// FETCH_SIZE=64MiB for a 128MiB input and effective write BW 1.6 TB/s vs the
// fill's 6.7 TB/s. The nt bit streams writes past the caches.

#define C3 0.35355339059327373f

typedef float nfloat4 __attribute__((ext_vector_type(4)));

__global__ __launch_bounds__(256) void swpt3_kernel(const float4* __restrict__ x,
                                                    float* __restrict__ out) {
    __shared__ float lds[1024];   // [node 0..7][j 0..127]

    const unsigned t   = threadIdx.x;
    const unsigned b   = blockIdx.x;
    const unsigned row = b >> 3;          // 8 chunks per row
    const unsigned ch  = b & 7u;

    const float4 v = x[(size_t)row * 2048u + ch * 256u + t];

    // level 1 within the float4
    const float s0 = v.x + v.y, d0 = v.x - v.y;
    const float s1 = v.z + v.w, d1 = v.z - v.w;
    // level 2 (unscaled): node-base nb = 4*b1 + 2*b2
    const float e0 = s0 + s1;   // nb=0
    const float e2 = s0 - s1;   // nb=2
    const float e4 = d0 + d1;   // nb=4
    const float e6 = d0 - d1;   // nb=6

    // level 3: adjacent lanes hold adjacent level-2 positions (parity = t&1).
    const int p = (int)(t & 1u);
    const float f0 = __shfl_xor(e0, 1);
    const float f2 = __shfl_xor(e2, 1);
    const float f4 = __shfl_xor(e4, 1);
    const float f6 = __shfl_xor(e6, 1);

    const float a0 = p ? -e0 : e0;
    const float a2 = p ? -e2 : e2;
    const float a4 = p ? -e4 : e4;
    const float a6 = p ? -e6 : e6;
    const float r0 = (f0 + a0) * C3;   // node p
    const float r2 = (f2 + a2) * C3;   // node 2+p
    const float r4 = (f4 + a4) * C3;   // node 4+p
    const float r6 = (f6 + a6) * C3;   // node 6+p

    const unsigned j = t >> 1;          // 0..127
    lds[(0u + p) * 128u + j] = r0;
    lds[(2u + p) * 128u + j] = r2;
    lds[(4u + p) * 128u + j] = r4;
    lds[(6u + p) * 128u + j] = r6;

    __syncthreads();

    // regroup: thread t stores float4 #t of the block's 1024 outputs
    const nfloat4 r = ((const nfloat4*)lds)[t];   // lds[t*4 .. t*4+3] = node t>>5, j=4*(t&31)
    const unsigned n = t >> 5;
    const unsigned m = t & 31u;
    nfloat4* o = (nfloat4*)(out + (size_t)row * 8192u + n * 1024u + ch * 128u + 4u * m);
    __builtin_nontemporal_store(r, o);   // nt: no L2/L3 write-allocate
}

extern "C" void kernel_launch(void* const* d_in, const int* in_sizes, int n_in,
                              void* d_out, int out_size, void* d_ws, size_t ws_size,
                              hipStream_t stream) {
    const float4* x = (const float4*)d_in[0];
    float* out = (float*)d_out;
    // 64*64*8192 floats = 8,388,608 float4 = 32768 blocks x 256 threads, exact.
    swpt3_kernel<<<32768, 256, 0, stream>>>(x, out);
}